// Round 15
// baseline (337.047 us; speedup 1.0000x reference)
//
#include <hip/hip_runtime.h>

#define DIN 55
#define HD 128
#define EB 8192          // edges per partition block
#define NBKT 512         // radix buckets (dst >> 8)

typedef unsigned short u16;
typedef unsigned int u32;
typedef _Float16 h8 __attribute__((ext_vector_type(8)));
typedef float f32x4 __attribute__((ext_vector_type(4)));

// ---- fp16 helpers ----
__device__ __forceinline__ u32 pkh(float a, float b) {
    auto r = __builtin_amdgcn_cvt_pkrtz(a, b);
    union { decltype(r) h; u32 u; } c; c.h = r; return c.u;
}
__device__ __forceinline__ u16 f2h(float v) {
    union { _Float16 f; u16 s; } c; c.f = (_Float16)v; return c.s;
}
__device__ __forceinline__ float h2f(u16 s) {
    union { u16 s; _Float16 f; } c; c.s = s; return (float)c.f;
}
__device__ __forceinline__ float2 h2f2(u32 u) {
    union { u32 v; _Float16 f[2]; } c; c.v = u;
    return make_float2((float)c.f[0], (float)c.f[1]);
}
// ---- fp8 e4m3 (OCP) helpers: HW pack/unpack ----
__device__ __forceinline__ u32 pk8(float a, float b, float c, float d) {
    int p = __builtin_amdgcn_cvt_pk_fp8_f32(a, b, 0, false);   // bytes 0,1
    p = __builtin_amdgcn_cvt_pk_fp8_f32(c, d, p, true);        // bytes 2,3
    return (u32)p;
}
#define ACC8FP8(P, A, B) { \
    auto u0 = __builtin_amdgcn_cvt_pk_f32_fp8((int)(P).x, false); \
    auto u1 = __builtin_amdgcn_cvt_pk_f32_fp8((int)(P).x, true);  \
    auto u2 = __builtin_amdgcn_cvt_pk_f32_fp8((int)(P).y, false); \
    auto u3 = __builtin_amdgcn_cvt_pk_f32_fp8((int)(P).y, true);  \
    A[0] += u0[0]; A[1] += u0[1]; A[2] += u1[0]; A[3] += u1[1];   \
    B[0] += u2[0]; B[1] += u2[1]; B[2] += u3[0]; B[3] += u3[1]; }

// ---------------- fused prep: rhist | weight frags | zero d_out ----------------
__global__ __launch_bounds__(256) void prep_kernel(const int* __restrict__ dst,
                                                   int* __restrict__ histT, int E, int nB,
                                                   const float* __restrict__ W1,
                                                   const float* __restrict__ W2,
                                                   const float* __restrict__ Wfc,
                                                   u16* __restrict__ wfrag,
                                                   float* __restrict__ outz, int out_n) {
    __shared__ int hh[NBKT];
    int t = threadIdx.x;
    if (blockIdx.x < (unsigned)nB) {
        int b = blockIdx.x;
        for (int i = t; i < NBKT; i += 256) hh[i] = 0;
        __syncthreads();
        int base = b * EB;
        int end = min(base + EB, E);
        for (int i = base + t; i < end; i += 256) atomicAdd(&hh[dst[i] >> 8], 1);
        __syncthreads();
        for (int k = t; k < NBKT; k += 256) histT[k * nB + b] = hh[k];
        return;
    }
    int bid = blockIdx.x - nB;
    int kc = t >> 6, lane = t & 63;
    if (bid < 48) {
        int m = bid >> 3, ft = bid & 7;
        int l = m >> 1, s = m & 1;
        const float* W = (s ? W2 : W1) + (size_t)l * HD * HD;
        int j = ft * 16 + (lane & 15);
        int k0 = kc * 32 + ((lane >> 4) << 3);
        h8 v;
#pragma unroll
        for (int i = 0; i < 8; i++)
            v[i] = (_Float16)W[(size_t)(k0 + i) * HD + j];
        *(h8*)&wfrag[(((size_t)bid * 4 + kc) * 64 + lane) * 8] = v;
    } else if (bid < 56) {
        if (kc < 2) {
            int ft = bid - 48;
            int j = ft * 16 + (lane & 15);
            int k0 = kc * 32 + ((lane >> 4) << 3);
            h8 v;
#pragma unroll
            for (int i = 0; i < 8; i++) {
                int k = k0 + i;
                v[i] = (k < DIN) ? (_Float16)Wfc[(size_t)k * HD + j] : (_Float16)0.f;
            }
            *(h8*)&wfrag[98304 + (((size_t)(ft * 2 + kc)) * 64 + lane) * 8] = v;
        }
    } else {
        int i = ((bid - 56) * 256 + t) * 2;
        if (i + 1 < out_n) *(float2*)&outz[i] = make_float2(0.f, 0.f);
        else if (i < out_n) outz[i] = 0.f;
    }
}

// per-1024-chunk inclusive scan; bsums[chunk] = chunk total
__global__ __launch_bounds__(256) void scan1_kernel(int* data, int* bsums, int n) {
    __shared__ int sT[256];
    int t = threadIdx.x;
    int base = blockIdx.x * 1024 + t * 4;
    int v0 = (base + 0 < n) ? data[base + 0] : 0;
    int v1 = (base + 1 < n) ? data[base + 1] : 0;
    int v2 = (base + 2 < n) ? data[base + 2] : 0;
    int v3 = (base + 3 < n) ? data[base + 3] : 0;
    v1 += v0; v2 += v1; v3 += v2;
    sT[t] = v3;
    __syncthreads();
    for (int off = 1; off < 256; off <<= 1) {
        int x = (t >= off) ? sT[t - off] : 0;
        __syncthreads();
        sT[t] += x;
        __syncthreads();
    }
    int excl = (t == 0) ? 0 : sT[t - 1];
    if (base + 0 < n) data[base + 0] = v0 + excl;
    if (base + 1 < n) data[base + 1] = v1 + excl;
    if (base + 2 < n) data[base + 2] = v2 + excl;
    if (base + 3 < n) data[base + 3] = v3 + excl;
    if (t == 255) bsums[blockIdx.x] = sT[255];
}

// ticketed scatter; chunk-base addition applied inline from an LDS scan of bsums
__global__ __launch_bounds__(256) void rpos_kernel(const int* __restrict__ src,
                                                   const int* __restrict__ dst,
                                                   const int* __restrict__ scanned,
                                                   const int* __restrict__ bsums,
                                                   u32* __restrict__ bpairs, int E, int nB,
                                                   int nChunks) {
    __shared__ int sBs[256];
    __shared__ int cur[NBKT];
    int t = threadIdx.x;
    {
        int v = (t < nChunks) ? bsums[t] : 0;
        sBs[t] = v;
        __syncthreads();
        for (int o = 1; o < 256; o <<= 1) {
            int x = (t >= o) ? sBs[t - o] : 0;
            __syncthreads();
            sBs[t] += x;
            __syncthreads();
        }
        sBs[t] -= v;                       // exclusive chunk bases
    }
    __syncthreads();
    for (int b = t; b < NBKT; b += 256) {
        int idx = b * nB + blockIdx.x;
        cur[b] = (idx == 0) ? 0 : scanned[idx - 1] + sBs[(idx - 1) >> 10];
    }
    __syncthreads();
    int base = blockIdx.x * EB;
    int end = min(base + EB, E);
    for (int i = base + t; i < end; i += 256) {
        int d = dst[i];
        int p = atomicAdd(&cur[d >> 8], 1);
        bpairs[p] = ((u32)src[i] << 8) | (u32)(d & 255);
    }
}

// fused per-bucket: count -> local scan -> write off -> scatter esrc (all LDS)
__global__ __launch_bounds__(256) void bfinal_kernel(const u32* __restrict__ bpairs,
                                                     const int* __restrict__ scanned,
                                                     const int* __restrict__ bsums,
                                                     int* __restrict__ off,
                                                     int* __restrict__ esrc, int N, int nB,
                                                     int nChunks) {
    __shared__ int sBs[256];
    __shared__ int cnt[256];
    __shared__ int sc[256];
    __shared__ int cur[256];
    int b = blockIdx.x, t = threadIdx.x;
    {
        int v = (t < nChunks) ? bsums[t] : 0;
        sBs[t] = v;
        __syncthreads();
        for (int o = 1; o < 256; o <<= 1) {
            int x = (t >= o) ? sBs[t - o] : 0;
            __syncthreads();
            sBs[t] += x;
            __syncthreads();
        }
        sBs[t] -= v;                       // exclusive chunk bases
    }
    __syncthreads();
    int iLo = b * nB - 1, iHi = (b + 1) * nB - 1;
    int lo = (b == 0) ? 0 : scanned[iLo] + sBs[iLo >> 10];
    int hi = scanned[iHi] + sBs[iHi >> 10];
    cnt[t] = 0;
    __syncthreads();
    for (int i = lo + t; i < hi; i += 256) atomicAdd(&cnt[bpairs[i] & 255u], 1);
    __syncthreads();
    int v = cnt[t];
    sc[t] = v;
    __syncthreads();
    for (int o = 1; o < 256; o <<= 1) {
        int x = (t >= o) ? sc[t - o] : 0;
        __syncthreads();
        sc[t] += x;
        __syncthreads();
    }
    int incl = sc[t];
    int gbase = lo + incl - v;
    int n = b * 256 + t;
    if (n < N) off[n] = gbase;
    if (n == N - 1) off[N] = lo + incl;
    cur[t] = gbase;
    __syncthreads();
    for (int i = lo + t; i < hi; i += 256) {
        u32 p = bpairs[i];
        int q = atomicAdd(&cur[p & 255u], 1);
        esrc[q] = (int)(p >> 8);
    }
}

// ---------------- node projection via MFMA: h8 = fp8(f16(x) @ Wfc + b_fc) ----------------
__global__ __launch_bounds__(512, 4) void fcm_kernel(const float* __restrict__ x,
                                                     const u16* __restrict__ wfc,
                                                     const float* __restrict__ bfc,
                                                     u32* __restrict__ h8p,
                                                     int N, int nTiles) {
    __shared__ u16 sX[17408];            // [128][136]: cols 0..63 = k (staging), 0..127 = f (epilogue)
    const int t = threadIdx.x;
    const int w = t >> 6, lane = t & 63;
    const int col = lane & 15;
    const int fq = lane >> 4;

    h8 aw0 = *(const h8*)&wfc[(((w << 1) + 0) * 64 + lane) * 8];
    h8 aw1 = *(const h8*)&wfc[(((w << 1) + 1) * 64 + lane) * 8];
    float4 bias = *(const float4*)&bfc[w * 16 + fq * 4];

    int tile = blockIdx.x;
    if (tile >= nTiles) return;
    int base = tile * 128;
    int nvalid = min(128, N - base);

    // stage x -> f16 rows (coalesced f32 loads, scalar u16 LDS writes)
    for (int i = t; i < nvalid * DIN; i += 512) {
        float v = x[(size_t)base * DIN + i];
        sX[(i / DIN) * 136 + (i % DIN)] = f2h(v);
    }
    for (int e = t; e < 128 * 9; e += 512)                 // zero pad k = 55..63
        sX[(e / 9) * 136 + DIN + (e % 9)] = 0;
    for (int i = nvalid * DIN + t; i < 128 * DIN; i += 512) // zero dead rows (last tile)
        sX[(i / DIN) * 136 + (i % DIN)] = 0;
    __syncthreads();

    f32x4 acc[8];
#pragma unroll
    for (int ntl = 0; ntl < 8; ntl++) {
        int n = ntl * 16 + col;
        h8 b0 = *(const h8*)&sX[n * 136 + fq * 8];
        h8 b1 = *(const h8*)&sX[n * 136 + 32 + fq * 8];
        f32x4 a;
        a[0] = bias.x; a[1] = bias.y; a[2] = bias.z; a[3] = bias.w;
        a = __builtin_amdgcn_mfma_f32_16x16x32_f16(aw0, b0, a, 0, 0, 0);
        a = __builtin_amdgcn_mfma_f32_16x16x32_f16(aw1, b1, a, 0, 0, 0);
        acc[ntl] = a;
    }
    __syncthreads();                     // all k reads done
#pragma unroll
    for (int ntl = 0; ntl < 8; ntl++) {
        int n = ntl * 16 + col;
        int f = w * 16 + fq * 4;
        *(uint2*)&sX[n * 136 + f] = make_uint2(pkh(acc[ntl][0], acc[ntl][1]),
                                               pkh(acc[ntl][2], acc[ntl][3]));
    }
    __syncthreads();
#pragma unroll
    for (int i = 0; i < 4; i++) {
        int c = t + 512 * i;
        int n = c >> 4, k8 = c & 15;
        if (n < nvalid) {
            uint4 v = *(const uint4*)&sX[n * 136 + k8 * 8];
            float2 f0 = h2f2(v.x), f1 = h2f2(v.y), f2 = h2f2(v.z), f3 = h2f2(v.w);
            *(uint2*)&h8p[(size_t)(base + n) * 32 + k8 * 2] =
                make_uint2(pk8(f0.x, f0.y, f1.x, f1.y), pk8(f2.x, f2.y, f3.x, f3.y));
        }
    }
}

// ---------------- fused GINConv layer: agg (LDS z) + MLP pair, 64 nodes/block ----------------
// Phase A: quarter-wave per node (2 nodes/quarter, 4-slot f32 ILP) gathers fp8 h
// rows from hin; f16 result written straight into the swizzled sA fragment slot
// (z never touches HBM). Phase B: GEMM1 -> sZ -> GEMM2 -> epilogue -> hout.
// hin != hout (ping-pong buffers): R14's in-place race is eliminated.
__global__ __launch_bounds__(512, 4) void gin_kernel(const u32* __restrict__ hin,
                                                     const int* __restrict__ off,
                                                     const int* __restrict__ esrc,
                                                     const u16* __restrict__ wf1,
                                                     const u16* __restrict__ wf2,
                                                     const float* __restrict__ b1,
                                                     const float* __restrict__ b2,
                                                     u32* __restrict__ hout,
                                                     const int* __restrict__ gid,
                                                     float* __restrict__ pout,
                                                     int N, int pool) {
    __shared__ u16 sA[8704];             // frag slots (8192 used) / epilogue rows [64][136]
    __shared__ u16 sZ[8704];             // z1 rows [64][136]
    __shared__ int sGid[64];

    const int t = threadIdx.x;
    const int w = t >> 6, lane = t & 63;   // w = this wave's f-tile (0..7)
    const int col = lane & 15;             // node within 16-tile
    const int fq = lane >> 4;              // feature quad

    const int base = blockIdx.x * 64;
    if (base >= N) return;
    const int nvalid = min(64, N - base);

    // weight frags + biases (independent of phase A; loads overlap the gather)
    h8 aw1[4], aw2[4];
#pragma unroll
    for (int kc = 0; kc < 4; kc++) {
        aw1[kc] = *(const h8*)&wf1[(((w << 2) + kc) << 9) + lane * 8];
        aw2[kc] = *(const h8*)&wf2[(((w << 2) + kc) << 9) + lane * 8];
    }
    float4 bias1 = *(const float4*)&b1[w * 16 + fq * 4];
    float4 bias2 = *(const float4*)&b2[w * 16 + fq * 4];
    if (pool && t < 64) sGid[t] = (base + t < N) ? gid[base + t] : 0;

    // --- Phase A: aggregate 64 nodes; quarter (t>>4) handles n_local and n_local+32 ---
    const int q = t & 15;
    const int qo = q * 2;                  // u32 offset within 32-u32 fp8 row
#pragma unroll
    for (int rep = 0; rep < 2; rep++) {
        int n_local = (t >> 4) + rep * 32;
        int n = base + n_local;
        uint4 v16 = make_uint4(0, 0, 0, 0);
        if (n < N) {
            int s0 = off[n], s1 = off[n + 1];
            f32x4 a0 = {0, 0, 0, 0}, b0 = a0, a1 = a0, b1v = a0;
            f32x4 a2 = a0, b2v = a0, a3 = a0, b3v = a0;
            int i = s0;
#define GATH(E, A, B) { uint2 p = *(const uint2*)&hin[(size_t)(E) * 32 + qo]; ACC8FP8(p, A, B) }
            for (; i + 4 <= s1; i += 4) {
                int e0 = esrc[i + 0], e1 = esrc[i + 1];
                int e2 = esrc[i + 2], e3 = esrc[i + 3];
                GATH(e0, a0, b0) GATH(e1, a1, b1v) GATH(e2, a2, b2v) GATH(e3, a3, b3v)
            }
            if (i + 2 <= s1) {
                int e0 = esrc[i], e1 = esrc[i + 1];
                GATH(e0, a0, b0) GATH(e1, a1, b1v)
                i += 2;
            }
            if (i < s1) {
                int e0 = esrc[i];
                GATH(e0, a2, b2v)
            }
            GATH(n, a3, b3v)               // self term: (1+eps)*h, eps=0
#undef GATH
            f32x4 sa = (a0 + a1) + (a2 + a3);
            f32x4 sb = (b0 + b1v) + (b2v + b3v);
            v16 = make_uint4(pkh(sa[0], sa[1]), pkh(sa[2], sa[3]),
                             pkh(sb[0], sb[1]), pkh(sb[2], sb[3]));
        }
        // write z (f16) directly into swizzled fragment slot for (n_local, k8=q)
        int nt = n_local >> 4, kc = q >> 2;
        int L = ((q & 3) << 4) | (n_local & 15);
        int slot = L ^ (kc << 1);
        *(uint4*)&sA[(((nt << 2) + kc) << 6 | slot) * 8] = v16;
    }
    __syncthreads();                     // B1: z frags (and sGid) ready

    // --- GEMM1: z1[f][n] = relu(W1^T x z^T + b1), 4 n-tiles ---
#pragma unroll
    for (int ntl = 0; ntl < 4; ntl++) {
        h8 bx[4];
#pragma unroll
        for (int kc = 0; kc < 4; kc++)
            bx[kc] = *(const h8*)&sA[(((ntl << 2) + kc) << 6 | (lane ^ (kc << 1))) * 8];
        f32x4 a0;
        a0[0] = bias1.x; a0[1] = bias1.y; a0[2] = bias1.z; a0[3] = bias1.w;
#pragma unroll
        for (int kc = 0; kc < 4; kc++)
            a0 = __builtin_amdgcn_mfma_f32_16x16x32_f16(aw1[kc], bx[kc], a0, 0, 0, 0);
        int n = ntl * 16 + col;
        int f = w * 16 + fq * 4;
        u32 lo = pkh(fmaxf(a0[0], 0.f), fmaxf(a0[1], 0.f));
        u32 hi = pkh(fmaxf(a0[2], 0.f), fmaxf(a0[3], 0.f));
        *(uint2*)&sZ[n * 136 + f] = make_uint2(lo, hi);
    }
    __syncthreads();                     // B2: z1 ready, all sA frag reads done

    // --- GEMM2: out[f][n] = W2^T x z1^T + b2; epilogue staged into sA rows ---
#pragma unroll
    for (int ntl = 0; ntl < 4; ntl++) {
        int n = ntl * 16 + col;
        h8 bz[4];
#pragma unroll
        for (int kc = 0; kc < 4; kc++)
            bz[kc] = *(const h8*)&sZ[n * 136 + kc * 32 + fq * 8];
        f32x4 a0;
        a0[0] = bias2.x; a0[1] = bias2.y; a0[2] = bias2.z; a0[3] = bias2.w;
#pragma unroll
        for (int kc = 0; kc < 4; kc++)
            a0 = __builtin_amdgcn_mfma_f32_16x16x32_f16(aw2[kc], bz[kc], a0, 0, 0, 0);
        int f = w * 16 + fq * 4;
        *(uint2*)&sA[n * 136 + f] = make_uint2(pkh(a0[0], a0[1]), pkh(a0[2], a0[3]));
    }
    __syncthreads();                     // B3: epilogue staged

    if (!pool) {
#pragma unroll
        for (int i = 0; i < 2; i++) {
            int c = t + 512 * i;
            int n = c >> 4, k8 = c & 15;
            if (n < nvalid) {
                uint4 v = *(const uint4*)&sA[n * 136 + k8 * 8];
                float2 f0 = h2f2(v.x), f1 = h2f2(v.y), f2 = h2f2(v.z), f3 = h2f2(v.w);
                *(uint2*)&hout[(size_t)(base + n) * 32 + k8 * 2] =
                    make_uint2(pk8(f0.x, f0.y, f1.x, f1.y), pk8(f2.x, f2.y, f3.x, f3.y));
            }
        }
    } else {
        // per-graph sum pool from LDS: 16-node windows, segmented by sorted gid
        int f = t & 127, r = t >> 7;       // 4 windows of 16 nodes
        int n0 = r * 16;
        if (n0 < nvalid) {
            int nlim = min(n0 + 16, nvalid);
            int curg = sGid[n0];
            float acc = 0.f;
            for (int n = n0; n < nlim; n++) {
                int g = sGid[n];
                if (g != curg) {
                    atomicAdd(&pout[(size_t)curg * HD + f], acc);
                    curg = g; acc = 0.f;
                }
                acc += h2f(sA[n * 136 + f]);
            }
            atomicAdd(&pout[(size_t)curg * HD + f], acc);
        }
    }
}

extern "C" void kernel_launch(void* const* d_in, const int* in_sizes, int n_in,
                              void* d_out, int out_size, void* d_ws, size_t ws_size,
                              hipStream_t stream) {
    (void)n_in; (void)ws_size;
    const float* x   = (const float*)d_in[0];
    const float* Wfc = (const float*)d_in[1];
    const float* bfc = (const float*)d_in[2];
    const float* W1  = (const float*)d_in[3];
    const float* b1  = (const float*)d_in[4];
    const float* W2  = (const float*)d_in[5];
    const float* b2  = (const float*)d_in[6];
    const int* src   = (const int*)d_in[7];
    const int* dst   = (const int*)d_in[8];
    const int* gid   = (const int*)d_in[9];

    int N = in_sizes[0] / DIN;       // 100000
    int E = in_sizes[7];             // 1600000
    int nTiles = (N + 127) / 128;
    int nTiles64 = (N + 63) / 64;
    int nB = (E + EB - 1) / EB;      // partition blocks (196)
    int nScan = NBKT * nB;           // histT length (100352)
    int nChunks = (nScan + 1023) / 1024;  // 98 scan chunks

    // workspace layout (~40 MB; ping-pong fp8 h buffers — no in-place layer update)
    u32* h8a = (u32*)d_ws;                        // N*32 u32 (fp8 rows, 12.8 MB)
    u32* h8b = h8a + (size_t)N * 32;              // N*32 u32 (fp8 rows, 12.8 MB)
    int* off    = (int*)(h8b + (size_t)N * 32);   // N+1
    int* esrc   = off + (N + 1);                  // E
    int* bsums2 = esrc + E;                       // 256
    int* histT  = bsums2 + 256;                   // NBKT*nB ints (401 KB)
    u32* bpairs = (u32*)(histT + nScan);          // E packed pairs
    u16* wfrag  = (u16*)(bpairs + E);             // 6 mlp + fc frags (213 KB), no alias

    // --- fused prep (rhist + weight frags + zero d_out) ---
    int zeroBlocks = (out_size + 511) / 512;
    prep_kernel<<<nB + 56 + zeroBlocks, 256, 0, stream>>>(dst, histT, E, nB,
                                                          W1, W2, Wfc, wfrag,
                                                          (float*)d_out, out_size);
    // --- rest of the radix partition chain ---
    scan1_kernel<<<nChunks, 256, 0, stream>>>(histT, bsums2, nScan);
    rpos_kernel<<<nB, 256, 0, stream>>>(src, dst, histT, bsums2, bpairs, E, nB, nChunks);
    bfinal_kernel<<<NBKT, 256, 0, stream>>>(bpairs, histT, bsums2, off, esrc, N, nB, nChunks);

    // --- node projection via MFMA (fp8 out) ---
    fcm_kernel<<<nTiles, 512, 0, stream>>>(x, wfrag + 98304, bfc, h8a, N, nTiles);

    // --- 3x fused GINConv (agg in LDS + MLP), ping-pong h; last layer pools ---
    u32* hin = h8a;
    u32* hout = h8b;
    for (int l = 0; l < 3; l++) {
        u16* wf1 = wfrag + (size_t)(2 * l) * 16384;
        u16* wf2 = wf1 + 16384;
        gin_kernel<<<nTiles64, 512, 0, stream>>>(hin, off, esrc, wf1, wf2,
                                                 b1 + (size_t)l * HD,
                                                 b2 + (size_t)l * HD, hout,
                                                 gid, (float*)d_out,
                                                 N, (l == 2) ? 1 : 0);
        u32* tmp = hin; hin = hout; hout = tmp;
    }
}

// Round 16
// 303.016 us; speedup vs baseline: 1.1123x; 1.1123x over previous
//
#include <hip/hip_runtime.h>

#define DIN 55
#define HD 128
#define EB 8192          // edges per partition block
#define NBKT 512         // radix buckets (dst >> 8)

typedef unsigned short u16;
typedef unsigned int u32;
typedef _Float16 h8 __attribute__((ext_vector_type(8)));
typedef float f32x4 __attribute__((ext_vector_type(4)));

// ---- fp16 helpers ----
__device__ __forceinline__ u32 pkh(float a, float b) {
    auto r = __builtin_amdgcn_cvt_pkrtz(a, b);
    union { decltype(r) h; u32 u; } c; c.h = r; return c.u;
}
__device__ __forceinline__ u16 f2h(float v) {
    union { _Float16 f; u16 s; } c; c.f = (_Float16)v; return c.s;
}
__device__ __forceinline__ float h2f(u16 s) {
    union { u16 s; _Float16 f; } c; c.s = s; return (float)c.f;
}
__device__ __forceinline__ float2 h2f2(u32 u) {
    union { u32 v; _Float16 f[2]; } c; c.v = u;
    return make_float2((float)c.f[0], (float)c.f[1]);
}
// ---- fp8 e4m3 (OCP) helpers: HW pack/unpack ----
__device__ __forceinline__ u32 pk8(float a, float b, float c, float d) {
    int p = __builtin_amdgcn_cvt_pk_fp8_f32(a, b, 0, false);   // bytes 0,1
    p = __builtin_amdgcn_cvt_pk_fp8_f32(c, d, p, true);        // bytes 2,3
    return (u32)p;
}
#define ACC8FP8(P, A, B) { \
    auto u0 = __builtin_amdgcn_cvt_pk_f32_fp8((int)(P).x, false); \
    auto u1 = __builtin_amdgcn_cvt_pk_f32_fp8((int)(P).x, true);  \
    auto u2 = __builtin_amdgcn_cvt_pk_f32_fp8((int)(P).y, false); \
    auto u3 = __builtin_amdgcn_cvt_pk_f32_fp8((int)(P).y, true);  \
    A[0] += u0[0]; A[1] += u0[1]; A[2] += u1[0]; A[3] += u1[1];   \
    B[0] += u2[0]; B[1] += u2[1]; B[2] += u3[0]; B[3] += u3[1]; }
// unpack uint2 of 8 fp8 -> uint4 of 8 f16
__device__ __forceinline__ uint4 up8to16(uint2 p) {
    auto u0 = __builtin_amdgcn_cvt_pk_f32_fp8((int)p.x, false);
    auto u1 = __builtin_amdgcn_cvt_pk_f32_fp8((int)p.x, true);
    auto u2 = __builtin_amdgcn_cvt_pk_f32_fp8((int)p.y, false);
    auto u3 = __builtin_amdgcn_cvt_pk_f32_fp8((int)p.y, true);
    return make_uint4(pkh(u0[0], u0[1]), pkh(u1[0], u1[1]),
                      pkh(u2[0], u2[1]), pkh(u3[0], u3[1]));
}

// ---------------- fused prep: rhist | weight frags | zero d_out ----------------
__global__ __launch_bounds__(256) void prep_kernel(const int* __restrict__ dst,
                                                   int* __restrict__ histT, int E, int nB,
                                                   const float* __restrict__ W1,
                                                   const float* __restrict__ W2,
                                                   const float* __restrict__ Wfc,
                                                   u16* __restrict__ wfrag,
                                                   float* __restrict__ outz, int out_n) {
    __shared__ int hh[NBKT];
    int t = threadIdx.x;
    if (blockIdx.x < (unsigned)nB) {
        int b = blockIdx.x;
        for (int i = t; i < NBKT; i += 256) hh[i] = 0;
        __syncthreads();
        int base = b * EB;
        int end = min(base + EB, E);
        for (int i = base + t; i < end; i += 256) atomicAdd(&hh[dst[i] >> 8], 1);
        __syncthreads();
        for (int k = t; k < NBKT; k += 256) histT[k * nB + b] = hh[k];
        return;
    }
    int bid = blockIdx.x - nB;
    int kc = t >> 6, lane = t & 63;
    if (bid < 48) {
        int m = bid >> 3, ft = bid & 7;
        int l = m >> 1, s = m & 1;
        const float* W = (s ? W2 : W1) + (size_t)l * HD * HD;
        int j = ft * 16 + (lane & 15);
        int k0 = kc * 32 + ((lane >> 4) << 3);
        h8 v;
#pragma unroll
        for (int i = 0; i < 8; i++)
            v[i] = (_Float16)W[(size_t)(k0 + i) * HD + j];
        *(h8*)&wfrag[(((size_t)bid * 4 + kc) * 64 + lane) * 8] = v;
    } else if (bid < 56) {
        if (kc < 2) {
            int ft = bid - 48;
            int j = ft * 16 + (lane & 15);
            int k0 = kc * 32 + ((lane >> 4) << 3);
            h8 v;
#pragma unroll
            for (int i = 0; i < 8; i++) {
                int k = k0 + i;
                v[i] = (k < DIN) ? (_Float16)Wfc[(size_t)k * HD + j] : (_Float16)0.f;
            }
            *(h8*)&wfrag[98304 + (((size_t)(ft * 2 + kc)) * 64 + lane) * 8] = v;
        }
    } else {
        int i = ((bid - 56) * 256 + t) * 2;
        if (i + 1 < out_n) *(float2*)&outz[i] = make_float2(0.f, 0.f);
        else if (i < out_n) outz[i] = 0.f;
    }
}

// per-1024-chunk inclusive scan; bsums[chunk] = chunk total
__global__ __launch_bounds__(256) void scan1_kernel(int* data, int* bsums, int n) {
    __shared__ int sT[256];
    int t = threadIdx.x;
    int base = blockIdx.x * 1024 + t * 4;
    int v0 = (base + 0 < n) ? data[base + 0] : 0;
    int v1 = (base + 1 < n) ? data[base + 1] : 0;
    int v2 = (base + 2 < n) ? data[base + 2] : 0;
    int v3 = (base + 3 < n) ? data[base + 3] : 0;
    v1 += v0; v2 += v1; v3 += v2;
    sT[t] = v3;
    __syncthreads();
    for (int off = 1; off < 256; off <<= 1) {
        int x = (t >= off) ? sT[t - off] : 0;
        __syncthreads();
        sT[t] += x;
        __syncthreads();
    }
    int excl = (t == 0) ? 0 : sT[t - 1];
    if (base + 0 < n) data[base + 0] = v0 + excl;
    if (base + 1 < n) data[base + 1] = v1 + excl;
    if (base + 2 < n) data[base + 2] = v2 + excl;
    if (base + 3 < n) data[base + 3] = v3 + excl;
    if (t == 255) bsums[blockIdx.x] = sT[255];
}

// ticketed scatter; chunk-base addition applied inline from an LDS scan of bsums
__global__ __launch_bounds__(256) void rpos_kernel(const int* __restrict__ src,
                                                   const int* __restrict__ dst,
                                                   const int* __restrict__ scanned,
                                                   const int* __restrict__ bsums,
                                                   u32* __restrict__ bpairs, int E, int nB,
                                                   int nChunks) {
    __shared__ int sBs[256];
    __shared__ int cur[NBKT];
    int t = threadIdx.x;
    {
        int v = (t < nChunks) ? bsums[t] : 0;
        sBs[t] = v;
        __syncthreads();
        for (int o = 1; o < 256; o <<= 1) {
            int x = (t >= o) ? sBs[t - o] : 0;
            __syncthreads();
            sBs[t] += x;
            __syncthreads();
        }
        sBs[t] -= v;                       // exclusive chunk bases
    }
    __syncthreads();
    for (int b = t; b < NBKT; b += 256) {
        int idx = b * nB + blockIdx.x;
        cur[b] = (idx == 0) ? 0 : scanned[idx - 1] + sBs[(idx - 1) >> 10];
    }
    __syncthreads();
    int base = blockIdx.x * EB;
    int end = min(base + EB, E);
    for (int i = base + t; i < end; i += 256) {
        int d = dst[i];
        int p = atomicAdd(&cur[d >> 8], 1);
        bpairs[p] = ((u32)src[i] << 8) | (u32)(d & 255);
    }
}

// fused per-bucket: count -> local scan -> write off -> scatter esrc (all LDS)
__global__ __launch_bounds__(256) void bfinal_kernel(const u32* __restrict__ bpairs,
                                                     const int* __restrict__ scanned,
                                                     const int* __restrict__ bsums,
                                                     int* __restrict__ off,
                                                     int* __restrict__ esrc, int N, int nB,
                                                     int nChunks) {
    __shared__ int sBs[256];
    __shared__ int cnt[256];
    __shared__ int sc[256];
    __shared__ int cur[256];
    int b = blockIdx.x, t = threadIdx.x;
    {
        int v = (t < nChunks) ? bsums[t] : 0;
        sBs[t] = v;
        __syncthreads();
        for (int o = 1; o < 256; o <<= 1) {
            int x = (t >= o) ? sBs[t - o] : 0;
            __syncthreads();
            sBs[t] += x;
            __syncthreads();
        }
        sBs[t] -= v;                       // exclusive chunk bases
    }
    __syncthreads();
    int iLo = b * nB - 1, iHi = (b + 1) * nB - 1;
    int lo = (b == 0) ? 0 : scanned[iLo] + sBs[iLo >> 10];
    int hi = scanned[iHi] + sBs[iHi >> 10];
    cnt[t] = 0;
    __syncthreads();
    for (int i = lo + t; i < hi; i += 256) atomicAdd(&cnt[bpairs[i] & 255u], 1);
    __syncthreads();
    int v = cnt[t];
    sc[t] = v;
    __syncthreads();
    for (int o = 1; o < 256; o <<= 1) {
        int x = (t >= o) ? sc[t - o] : 0;
        __syncthreads();
        sc[t] += x;
        __syncthreads();
    }
    int incl = sc[t];
    int gbase = lo + incl - v;
    int n = b * 256 + t;
    if (n < N) off[n] = gbase;
    if (n == N - 1) off[N] = lo + incl;
    cur[t] = gbase;
    __syncthreads();
    for (int i = lo + t; i < hi; i += 256) {
        u32 p = bpairs[i];
        int q = atomicAdd(&cur[p & 255u], 1);
        esrc[q] = (int)(p >> 8);
    }
}

// ---------------- edge aggregation: z = h_self + sum h[esrc]  (fp8 in, fp8 out) ----------------
// h stored fp8 e4m3 (128 B/row): halves the gather bytes, cache lines, and the
// compulsory per-XCD L2-miss footprint (R8/R10/R12: transaction wall confirmed by
// the proportional fp8 gain). z also fp8. Accumulation in f32.
__global__ __launch_bounds__(256) void agg_kernel(const u32* __restrict__ h8p,
                                                  const int* __restrict__ off,
                                                  const int* __restrict__ esrc,
                                                  u32* __restrict__ z8, int N) {
    int t = threadIdx.x;
    int q = t & 15;                        // feature chunk within row (8 feats)
    int n = blockIdx.x * 16 + (t >> 4);    // node handled by this quarter
    if (n >= N) return;
    int s0 = off[n], s1 = off[n + 1];
    const int qo = q * 2;                  // u32 offset within 32-u32 row
    f32x4 a0 = {0, 0, 0, 0}, b0 = a0, a1 = a0, b1 = a0;
    f32x4 a2 = a0, b2 = a0, a3 = a0, b3 = a0;
    int i = s0;
#define GATH(E, A, B) { uint2 p = *(const uint2*)&h8p[(size_t)(E) * 32 + qo]; ACC8FP8(p, A, B) }
    for (; i + 4 <= s1; i += 4) {
        int e0 = esrc[i + 0], e1 = esrc[i + 1];
        int e2 = esrc[i + 2], e3 = esrc[i + 3];
        GATH(e0, a0, b0) GATH(e1, a1, b1) GATH(e2, a2, b2) GATH(e3, a3, b3)
    }
    if (i + 2 <= s1) {
        int e0 = esrc[i], e1 = esrc[i + 1];
        GATH(e0, a0, b0) GATH(e1, a1, b1)
        i += 2;
    }
    if (i < s1) {
        int e0 = esrc[i];
        GATH(e0, a2, b2)
    }
    GATH(n, a3, b3)                        // self term: (1+eps)*h, eps=0
#undef GATH
    f32x4 sa = (a0 + a1) + (a2 + a3);
    f32x4 sb = (b0 + b1) + (b2 + b3);
    *(uint2*)&z8[(size_t)n * 32 + qo] =
        make_uint2(pk8(sa[0], sa[1], sa[2], sa[3]), pk8(sb[0], sb[1], sb[2], sb[3]));
}

// ---------------- node projection via MFMA: h8 = fp8(f16(x) @ Wfc + b_fc) ----------------
__global__ __launch_bounds__(512, 4) void fcm_kernel(const float* __restrict__ x,
                                                     const u16* __restrict__ wfc,
                                                     const float* __restrict__ bfc,
                                                     u32* __restrict__ h8p,
                                                     int N, int nTiles) {
    __shared__ u16 sX[17408];            // [128][136]: cols 0..63 = k (staging), 0..127 = f (epilogue)
    const int t = threadIdx.x;
    const int w = t >> 6, lane = t & 63;
    const int col = lane & 15;
    const int fq = lane >> 4;

    h8 aw0 = *(const h8*)&wfc[(((w << 1) + 0) * 64 + lane) * 8];
    h8 aw1 = *(const h8*)&wfc[(((w << 1) + 1) * 64 + lane) * 8];
    float4 bias = *(const float4*)&bfc[w * 16 + fq * 4];

    int tile = blockIdx.x;
    if (tile >= nTiles) return;
    int base = tile * 128;
    int nvalid = min(128, N - base);

    // stage x -> f16 rows (coalesced f32 loads, scalar u16 LDS writes)
    for (int i = t; i < nvalid * DIN; i += 512) {
        float v = x[(size_t)base * DIN + i];
        sX[(i / DIN) * 136 + (i % DIN)] = f2h(v);
    }
    for (int e = t; e < 128 * 9; e += 512)                 // zero pad k = 55..63
        sX[(e / 9) * 136 + DIN + (e % 9)] = 0;
    for (int i = nvalid * DIN + t; i < 128 * DIN; i += 512) // zero dead rows (last tile)
        sX[(i / DIN) * 136 + (i % DIN)] = 0;
    __syncthreads();

    f32x4 acc[8];
#pragma unroll
    for (int ntl = 0; ntl < 8; ntl++) {
        int n = ntl * 16 + col;
        h8 b0 = *(const h8*)&sX[n * 136 + fq * 8];
        h8 b1 = *(const h8*)&sX[n * 136 + 32 + fq * 8];
        f32x4 a;
        a[0] = bias.x; a[1] = bias.y; a[2] = bias.z; a[3] = bias.w;
        a = __builtin_amdgcn_mfma_f32_16x16x32_f16(aw0, b0, a, 0, 0, 0);
        a = __builtin_amdgcn_mfma_f32_16x16x32_f16(aw1, b1, a, 0, 0, 0);
        acc[ntl] = a;
    }
    __syncthreads();                     // all k reads done
#pragma unroll
    for (int ntl = 0; ntl < 8; ntl++) {
        int n = ntl * 16 + col;
        int f = w * 16 + fq * 4;
        *(uint2*)&sX[n * 136 + f] = make_uint2(pkh(acc[ntl][0], acc[ntl][1]),
                                               pkh(acc[ntl][2], acc[ntl][3]));
    }
    __syncthreads();
#pragma unroll
    for (int i = 0; i < 4; i++) {
        int c = t + 512 * i;
        int n = c >> 4, k8 = c & 15;
        if (n < nvalid) {
            uint4 v = *(const uint4*)&sX[n * 136 + k8 * 8];
            float2 f0 = h2f2(v.x), f1 = h2f2(v.y), f2 = h2f2(v.z), f3 = h2f2(v.w);
            *(uint2*)&h8p[(size_t)(base + n) * 32 + k8 * 2] =
                make_uint2(pk8(f0.x, f0.y, f1.x, f1.y), pk8(f2.x, f2.y, f3.x, f3.y));
        }
    }
}

// ---------------- fused MLP pair, 64-node tiles, one tile per block ----------------
// 512 threads, wave = 1 f-tile x 4 n-tiles. LDS ~34 KB -> 4 blocks/CU = 32 waves/CU.
// Input z fp8 (unpacked to f16 in staging); output h fp8 for the next agg's gather.
// Last layer (pool=1): epilogue pools per-graph sums from LDS (gid sorted, 16-node
// windows); h is never written.
__global__ __launch_bounds__(512, 4) void mlp_pair_kernel(const u32* __restrict__ in8,
                                                          const u16* __restrict__ wf1,
                                                          const u16* __restrict__ wf2,
                                                          const float* __restrict__ b1,
                                                          const float* __restrict__ b2,
                                                          u32* __restrict__ hout,
                                                          const int* __restrict__ gid,
                                                          float* __restrict__ pout,
                                                          int N, int pool) {
    __shared__ u16 sA[8704];             // frag slots (8192 used) / epilogue rows [64][136]
    __shared__ u16 sZ[8704];             // z1 rows [64][136]
    __shared__ int sGid[64];

    const int t = threadIdx.x;
    const int w = t >> 6, lane = t & 63;   // w = this wave's f-tile (0..7)
    const int col = lane & 15;             // node within 16-tile
    const int fq = lane >> 4;              // feature quad

    const int base = blockIdx.x * 64;
    if (base >= N) return;
    const int nvalid = min(64, N - base);

    // per-wave weight fragments from global (L2-hot after first blocks)
    h8 aw1[4], aw2[4];
#pragma unroll
    for (int kc = 0; kc < 4; kc++) {
        aw1[kc] = *(const h8*)&wf1[(((w << 2) + kc) << 9) + lane * 8];
        aw2[kc] = *(const h8*)&wf2[(((w << 2) + kc) << 9) + lane * 8];
    }
    float4 bias1 = *(const float4*)&b1[w * 16 + fq * 4];
    float4 bias2 = *(const float4*)&b2[w * 16 + fq * 4];

    // stage input tile (fp8 -> f16) into swizzled fragment slots
#pragma unroll
    for (int i = 0; i < 2; i++) {
        int c = t + 512 * i;               // c in [0,1024): n = c>>4, k8 = c&15
        int n = c >> 4, k8 = c & 15;
        uint2 raw = make_uint2(0, 0);
        if (n < nvalid)
            raw = *(const uint2*)&in8[(size_t)(base + n) * 32 + k8 * 2];
        uint4 v16 = up8to16(raw);
        int nt = n >> 4, kc = k8 >> 2;
        int L = ((k8 & 3) << 4) | (n & 15);
        int slot = L ^ (kc << 1);
        *(uint4*)&sA[(((nt << 2) + kc) << 6 | slot) * 8] = v16;
    }
    if (pool && t < 64) sGid[t] = (base + t < N) ? gid[base + t] : 0;
    __syncthreads();                     // B1: frags (and sGid) ready

    // --- GEMM1: z1[f][n] = relu(W1^T x in^T + b1), 4 n-tiles ---
#pragma unroll
    for (int ntl = 0; ntl < 4; ntl++) {
        h8 bx[4];
#pragma unroll
        for (int kc = 0; kc < 4; kc++)
            bx[kc] = *(const h8*)&sA[(((ntl << 2) + kc) << 6 | (lane ^ (kc << 1))) * 8];
        f32x4 a0;
        a0[0] = bias1.x; a0[1] = bias1.y; a0[2] = bias1.z; a0[3] = bias1.w;
#pragma unroll
        for (int kc = 0; kc < 4; kc++)
            a0 = __builtin_amdgcn_mfma_f32_16x16x32_f16(aw1[kc], bx[kc], a0, 0, 0, 0);
        int n = ntl * 16 + col;
        int f = w * 16 + fq * 4;
        u32 lo = pkh(fmaxf(a0[0], 0.f), fmaxf(a0[1], 0.f));
        u32 hi = pkh(fmaxf(a0[2], 0.f), fmaxf(a0[3], 0.f));
        *(uint2*)&sZ[n * 136 + f] = make_uint2(lo, hi);
    }
    __syncthreads();                     // B2: z1 ready, all frag reads done

    // --- GEMM2: out[f][n] = W2^T x z1^T + b2; epilogue staged into sA rows ---
#pragma unroll
    for (int ntl = 0; ntl < 4; ntl++) {
        int n = ntl * 16 + col;
        h8 bz[4];
#pragma unroll
        for (int kc = 0; kc < 4; kc++)
            bz[kc] = *(const h8*)&sZ[n * 136 + kc * 32 + fq * 8];
        f32x4 a0;
        a0[0] = bias2.x; a0[1] = bias2.y; a0[2] = bias2.z; a0[3] = bias2.w;
#pragma unroll
        for (int kc = 0; kc < 4; kc++)
            a0 = __builtin_amdgcn_mfma_f32_16x16x32_f16(aw2[kc], bz[kc], a0, 0, 0, 0);
        int f = w * 16 + fq * 4;
        *(uint2*)&sA[n * 136 + f] = make_uint2(pkh(a0[0], a0[1]), pkh(a0[2], a0[3]));
    }
    __syncthreads();                     // B3: epilogue staged

    if (!pool) {
#pragma unroll
        for (int i = 0; i < 2; i++) {
            int c = t + 512 * i;
            int n = c >> 4, k8 = c & 15;
            if (n < nvalid) {
                uint4 v = *(const uint4*)&sA[n * 136 + k8 * 8];
                float2 f0 = h2f2(v.x), f1 = h2f2(v.y), f2 = h2f2(v.z), f3 = h2f2(v.w);
                *(uint2*)&hout[(size_t)(base + n) * 32 + k8 * 2] =
                    make_uint2(pk8(f0.x, f0.y, f1.x, f1.y), pk8(f2.x, f2.y, f3.x, f3.y));
            }
        }
    } else {
        // per-graph sum pool from LDS: 16-node windows, segmented by sorted gid
        int f = t & 127, r = t >> 7;       // 4 windows of 16 nodes
        int n0 = r * 16;
        if (n0 < nvalid) {
            int nlim = min(n0 + 16, nvalid);
            int curg = sGid[n0];
            float acc = 0.f;
            for (int n = n0; n < nlim; n++) {
                int g = sGid[n];
                if (g != curg) {
                    atomicAdd(&pout[(size_t)curg * HD + f], acc);
                    curg = g; acc = 0.f;
                }
                acc += h2f(sA[n * 136 + f]);
            }
            atomicAdd(&pout[(size_t)curg * HD + f], acc);
        }
    }
}

extern "C" void kernel_launch(void* const* d_in, const int* in_sizes, int n_in,
                              void* d_out, int out_size, void* d_ws, size_t ws_size,
                              hipStream_t stream) {
    (void)n_in; (void)ws_size;
    const float* x   = (const float*)d_in[0];
    const float* Wfc = (const float*)d_in[1];
    const float* bfc = (const float*)d_in[2];
    const float* W1  = (const float*)d_in[3];
    const float* b1  = (const float*)d_in[4];
    const float* W2  = (const float*)d_in[5];
    const float* b2  = (const float*)d_in[6];
    const int* src   = (const int*)d_in[7];
    const int* dst   = (const int*)d_in[8];
    const int* gid   = (const int*)d_in[9];

    int N = in_sizes[0] / DIN;       // 100000
    int E = in_sizes[7];             // 1600000
    int nTiles = (N + 127) / 128;
    int nTiles64 = (N + 63) / 64;
    int nB = (E + EB - 1) / EB;      // partition blocks (196)
    int nScan = NBKT * nB;           // histT length (100352)
    int nChunks = (nScan + 1023) / 1024;  // 98 scan chunks

    // workspace layout (~40 MB; fp8 h AND fp8 z)
    u32* h8p = (u32*)d_ws;                        // N*32 u32 (fp8 rows, 12.8 MB)
    u32* z8  = h8p + (size_t)N * 32;              // N*32 u32 (fp8 rows, 12.8 MB)
    int* off    = (int*)(z8 + (size_t)N * 32);    // N+1
    int* esrc   = off + (N + 1);                  // E
    int* bsums2 = esrc + E;                       // 256
    int* histT  = bsums2 + 256;                   // NBKT*nB ints (401 KB)
    u32* bpairs = (u32*)(histT + nScan);          // E packed pairs
    u16* wfrag  = (u16*)(bpairs + E);             // 6 mlp + fc frags (213 KB), no alias

    // --- fused prep (rhist + weight frags + zero d_out) ---
    int zeroBlocks = (out_size + 511) / 512;
    prep_kernel<<<nB + 56 + zeroBlocks, 256, 0, stream>>>(dst, histT, E, nB,
                                                          W1, W2, Wfc, wfrag,
                                                          (float*)d_out, out_size);
    // --- rest of the radix partition chain ---
    scan1_kernel<<<nChunks, 256, 0, stream>>>(histT, bsums2, nScan);
    rpos_kernel<<<nB, 256, 0, stream>>>(src, dst, histT, bsums2, bpairs, E, nB, nChunks);
    bfinal_kernel<<<NBKT, 256, 0, stream>>>(bpairs, histT, bsums2, off, esrc, N, nB, nChunks);

    // --- node projection via MFMA (fp8 out) ---
    fcm_kernel<<<nTiles, 512, 0, stream>>>(x, wfrag + 98304, bfc, h8p, N, nTiles);

    // --- 3x GINConv; last layer pools directly from LDS (no h write) ---
    for (int l = 0; l < 3; l++) {
        u16* wf1 = wfrag + (size_t)(2 * l) * 16384;
        u16* wf2 = wf1 + 16384;
        agg_kernel<<<(N + 15) / 16, 256, 0, stream>>>(h8p, off, esrc, z8, N);
        mlp_pair_kernel<<<nTiles64, 512, 0, stream>>>(z8, wf1, wf2,
                                                      b1 + (size_t)l * HD,
                                                      b2 + (size_t)l * HD, h8p,
                                                      gid, (float*)d_out,
                                                      N, (l == 2) ? 1 : 0);
    }
}